// Round 8
// baseline (290.086 us; speedup 1.0000x reference)
//
#include <hip/hip_runtime.h>
#include <stdint.h>

// ---------------------------------------------------------------------------
// PDG2Seq_GCN: B=16, N=1024, C=O=64, D=10, CHEB_K=2 (K=5 stacked terms)
// Round 14: R13 skeleton with a restructured hop tile: 128 output rows per
// block, 512 thr (8 waves). Per-wave work identical (16 rows, 8 MFMA/stage)
// but stage-barrier rounds halve (256 blocks vs 512), B-panel redundancy
// halves (staged 8x not 16x per slice), resident TLP unchanged (8 waves/CU).
// cvt+prep fused into one launch (R8's cvtprep, proven); final = R8's
// global-read final (proven) — kills R13's per-d DMA-drain serialization.
// Launches: cvtprep, hop1, hop2, final (4 kernels).
// ---------------------------------------------------------------------------

typedef __attribute__((ext_vector_type(4))) float f32x4;
typedef __attribute__((ext_vector_type(8))) short s16x8;
typedef __attribute__((ext_vector_type(8))) __bf16 bf16x8;

__device__ __forceinline__ unsigned short f2bf(float f) {
  union { float f; uint32_t u; } v; v.f = f;
  uint32_t r = v.u + 0x7FFFu + ((v.u >> 16) & 1u);   // RNE
  return (unsigned short)(r >> 16);
}
__device__ __forceinline__ uint32_t pack2(float a, float b) {
  return (uint32_t)f2bf(a) | ((uint32_t)f2bf(b) << 16);
}

union FragU { s16x8 s; bf16x8 b; uint32_t u[4]; };

__device__ __forceinline__ void async_cp16(const void* g, void* l) {
  __builtin_amdgcn_global_load_lds(
      (const __attribute__((address_space(1))) void*)g,
      (__attribute__((address_space(3))) void*)l, 16, 0, 0);
}

// ---------------------------------------------------------------------------
// K0 cvtprep (R8, proven): blocks 0..8191: adj f32 -> adjb bf16;
//   8192..8447: x -> XT0 bf16 [b][c][n] + X0b bf16 [b][n][c];
//   8448..8497: wp -> wpTb bf16 linear [d][o][ki].
// ---------------------------------------------------------------------------
__global__ __launch_bounds__(256) void cvtprep(
    const float* __restrict__ adj, unsigned short* __restrict__ adjb,
    const float* __restrict__ x, const float* __restrict__ wp,
    unsigned short* __restrict__ XT0, unsigned short* __restrict__ X0b,
    unsigned short* __restrict__ wpTb) {
  __shared__ __align__(16) char smem[17160];
  const int tid = threadIdx.x;
  const int bid = blockIdx.x;

  if (bid < 8192) {
    const size_t stride = (size_t)8192 * 256 * 8;
    for (size_t p = ((size_t)bid * 256 + tid) * 8; p < 33554432u;
         p += stride) {
      f32x4 a = *(const f32x4*)(adj + p);
      f32x4 b = *(const f32x4*)(adj + p + 4);
      union { s16x8 s; uint32_t u[4]; } o;
      o.u[0] = pack2(a[0], a[1]);
      o.u[1] = pack2(a[2], a[3]);
      o.u[2] = pack2(b[0], b[1]);
      o.u[3] = pack2(b[2], b[3]);
      *(s16x8*)(adjb + p) = o.s;
    }
    return;
  }

  const int pid = bid - 8192;
  if (pid < 256) {
    unsigned short (*tl)[72] = (unsigned short(*)[72])smem;
    const int b = pid >> 4, n0 = (pid & 15) * 64;
    {
      const int c4 = (tid & 15) * 4;
#pragma unroll
      for (int i = 0; i < 4; ++i) {
        const int row = (tid >> 4) + i * 16;
        f32x4 v =
            *(const f32x4*)(x + ((size_t)(b * 1024 + n0 + row)) * 64 + c4);
        const uint32_t w0 = pack2(v[0], v[1]);
        const uint32_t w1 = pack2(v[2], v[3]);
        *(uint32_t*)&tl[row][c4]     = w0;
        *(uint32_t*)&tl[row][c4 + 2] = w1;
        const uint64_t wq = (uint64_t)w0 | ((uint64_t)w1 << 32);
        *(uint64_t*)(X0b + ((size_t)(b * 1024 + n0 + row)) * 64 + c4) = wq;
      }
    }
    __syncthreads();
    {
      const int c = tid >> 2;
      const int nch = (tid & 3) * 16;
      s16x8 s0, s1;
#pragma unroll
      for (int j = 0; j < 8; ++j) {
        s0[j] = (short)tl[nch + j][c];
        s1[j] = (short)tl[nch + 8 + j][c];
      }
      unsigned short* p = XT0 + (size_t)(b * 64 + c) * 1024 + n0 + nch;
      *(s16x8*)p = s0;
      *(s16x8*)(p + 8) = s1;
    }
  } else {
    float (*tl)[65] = (float(*)[65])smem;
    const int jj = pid - 256;
    const int d = jj / 5, ki0 = (jj % 5) * 64;
    const float* src = wp + (size_t)d * 20480;
    {
      const int o4 = (tid & 15) * 4;
#pragma unroll
      for (int i = 0; i < 4; ++i) {
        const int row = (tid >> 4) + i * 16;
        f32x4 v = *(const f32x4*)(src + (size_t)(ki0 + row) * 64 + o4);
        tl[row][o4] = v[0]; tl[row][o4 + 1] = v[1];
        tl[row][o4 + 2] = v[2]; tl[row][o4 + 3] = v[3];
      }
    }
    __syncthreads();
    {
      const int o = tid >> 2;
      const int kch = (tid & 3) * 16;
      unsigned short* dst =
          wpTb + (size_t)d * 20480 + (size_t)o * 320 + ki0 + kch;
      s16x8 s0, s1;
#pragma unroll
      for (int j = 0; j < 8; ++j) {
        s0[j] = (short)f2bf(tl[kch + j][o]);
        s1[j] = (short)f2bf(tl[kch + 8 + j][o]);
      }
      *(s16x8*)dst = s0;
      *(s16x8*)(dst + 8) = s1;
    }
  }
}

// ---------------------------------------------------------------------------
// hop body v2: out[128 rows][64] = A[1024x1024]bf16 @ X[1024x64]bf16.
// 512 thr / 8 waves, each wave 16 rows (same per-wave shape as R13).
// Per stage: A 16KB (2 DMA/wave) + B 8KB (1 DMA/wave), 2-buf 48KB LDS,
// 1 __syncthreads per stage (vmcnt drain), XOR chunk swizzle on the global
// source, swizzled frag reads. Epilogue: 128x65 f32 tile transpose in LDS.
// ---------------------------------------------------------------------------
__device__ __forceinline__ void hop_body(
    char* smem, const unsigned short* __restrict__ A,
    const unsigned short* __restrict__ XT, unsigned short* __restrict__ Xoutb,
    unsigned short* __restrict__ XTout, int write_xt, int rowbase) {
  const int tid = threadIdx.x;
  const int wave = tid >> 6, lane = tid & 63;
  const int l15 = lane & 15, q = lane >> 4;

  unsigned short* const Ast = (unsigned short*)smem;           // [2][128][64]
  unsigned short* const Bst = (unsigned short*)smem + 16384;   // [2][64][64]

  const int sub = lane >> 3;            // row-in-8
  const int ch = lane & 7;              // 8-short chunk
  const unsigned short* asrc[2];
  int aldso[2];
#pragma unroll
  for (int i = 0; i < 2; ++i) {
    const int r = wave * 16 + i * 8 + sub;
    asrc[i] = A + (size_t)(rowbase + r) * 1024 + (ch ^ sub) * 8;
    aldso[i] = (wave * 16 + i * 8) * 64;
  }
  const int rc = wave * 8 + (lane >> 3);        // B row = channel c
  const unsigned short* bsrc =
      XT + (size_t)rc * 1024 + ((lane & 7) ^ (rc & 7)) * 8;
  const int bldso = wave * 512;

  f32x4 acc[4];
#pragma unroll
  for (int t = 0; t < 4; ++t) acc[t] = (f32x4){0.f, 0.f, 0.f, 0.f};

  auto issue = [&](int s, int k0) {
#pragma unroll
    for (int i = 0; i < 2; ++i)
      async_cp16(asrc[i] + k0, Ast + s * 8192 + aldso[i]);
    async_cp16(bsrc + k0, Bst + s * 4096 + bldso);
  };
  const int sw = l15 & 7;
  auto compute = [&](int s) {
    const unsigned short* Ab = Ast + s * 8192 + (wave * 16 + l15) * 64;
    const unsigned short* Bb = Bst + s * 4096 + l15 * 64;
#pragma unroll
    for (int h = 0; h < 2; ++h) {
      const int cko = ((h * 4 + q) ^ sw) * 8;
      FragU af;
      af.s = *(const s16x8*)(Ab + cko);
#pragma unroll
      for (int t = 0; t < 4; ++t) {
        FragU bf;
        bf.s = *(const s16x8*)(Bb + t * 1024 + cko);
        acc[t] = __builtin_amdgcn_mfma_f32_16x16x32_bf16(af.b, bf.b, acc[t],
                                                         0, 0, 0);
      }
    }
  };

  issue(0, 0);
#pragma unroll 1
  for (int kt = 0; kt < 16; ++kt) {
    const int cur = kt & 1;
    __syncthreads();                   // stage kt landed (vmcnt drain)
    if (kt + 1 < 16) issue(cur ^ 1, (kt + 1) * 64);
    compute(cur);
  }

  // Epilogue: 128x64 transpose via LDS (reuse stage memory), bf16 write-out
  __syncthreads();
  float (*tile)[65] = (float(*)[65])smem;              // 33.3 KB
#pragma unroll
  for (int t = 0; t < 4; ++t)
#pragma unroll
    for (int rr = 0; rr < 4; ++rr)
      tile[wave * 16 + q * 4 + rr][t * 16 + l15] = acc[t][rr];
  __syncthreads();

  {  // node-major bf16 [n][c]
    const int row = tid >> 2;                  // 0..127
    const int cb = (tid & 3) * 16;
    unsigned short* __restrict__ outp =
        Xoutb + (size_t)(rowbase + row) * 64 + cb;
    s16x8 s0, s1;
#pragma unroll
    for (int j = 0; j < 8; ++j) {
      s0[j] = (short)f2bf(tile[row][cb + j]);
      s1[j] = (short)f2bf(tile[row][cb + 8 + j]);
    }
    *(s16x8*)outp = s0;
    *(s16x8*)(outp + 8) = s1;
  }
  if (write_xt) {  // c-major bf16 [c][n] for next hop
    const int c = tid >> 3;                    // 0..63
    const int nch = (tid & 7) * 16;            // 0..112
    unsigned short* __restrict__ xtp = XTout + (size_t)c * 1024 + rowbase + nch;
    s16x8 s0, s1;
#pragma unroll
    for (int j = 0; j < 8; ++j) {
      s0[j] = (short)f2bf(tile[nch + j][c]);
      s1[j] = (short)f2bf(tile[nch + 8 + j][c]);
    }
    *(s16x8*)xtp = s0;
    *(s16x8*)(xtp + 8) = s1;
  }
}

// ---------------------------------------------------------------------------
// K1 hop1: adjb bf16 (LLC-warm) -> X1b + XT1. grid (8, 32), 512 thr.
// ---------------------------------------------------------------------------
__global__ __launch_bounds__(512, 2) void hop1_kernel(
    const unsigned short* __restrict__ adjb,
    const unsigned short* __restrict__ XT0, unsigned short* __restrict__ X1b,
    unsigned short* __restrict__ XT1) {
  __shared__ __align__(16) char smem[49152];
  const int bx = blockIdx.x, slice = blockIdx.y, b = slice & 15;
  hop_body(smem, adjb + (size_t)slice * 1048576, XT0 + (size_t)b * 65536,
           X1b + (size_t)slice * 65536, XT1 + (size_t)slice * 65536, 1,
           bx * 128);
}

// ---------------------------------------------------------------------------
// K2 hop2, reversed block order (LLC-hot adjb tail first).
// ---------------------------------------------------------------------------
__global__ __launch_bounds__(512, 2) void hop2_kernel(
    const unsigned short* __restrict__ adjb,
    const unsigned short* __restrict__ XT1, unsigned short* __restrict__ X2b) {
  __shared__ __align__(16) char smem[49152];
  const int bx = 7 - (int)blockIdx.x;
  const int slice = 31 - (int)blockIdx.y;
  hop_body(smem, adjb + (size_t)slice * 1048576, XT1 + (size_t)slice * 65536,
           X2b + (size_t)slice * 65536, (unsigned short*)0, 0, bx * 128);
}

// ---------------------------------------------------------------------------
// K3 final (R8, proven): out[b,n,o] = sum_d emb[n,d]*(xg[b,n,:]@WpT_d) + bias.
// Weights read per-d straight from L2-resident linear wpTb (410 KB shared).
// 2 nodes/block, 2 waves per node (o halves). grid 512, block 256.
// ---------------------------------------------------------------------------
__global__ __launch_bounds__(256, 2) void final_kernel(
    const unsigned short* __restrict__ X0b,
    const unsigned short* __restrict__ X1b,
    const unsigned short* __restrict__ X2b,
    const unsigned short* __restrict__ wpTb, const float* __restrict__ emb,
    const float* __restrict__ bp, float* __restrict__ out) {
  const int tid = threadIdx.x, bid = blockIdx.x;
  const int wave = tid >> 6, lane = tid & 63;
  const int l15 = lane & 15, q = lane >> 4;
  const int nd = wave >> 1, oh = wave & 1;
  const int n = bid * 2 + nd;

  FragU af10[10];
#pragma unroll
  for (int ks = 0; ks < 10; ++ks) {
    const int k = ks >> 1;
    const int cc0 = (ks & 1) * 32 + q * 8;
    const unsigned short* srcp;
    if (k == 0) {
      srcp = X0b + ((size_t)l15 * 1024 + n) * 64 + cc0;
    } else {
      const unsigned short* arr = (k == 1 || k == 3) ? X1b : X2b;
      const int s = (k >= 3) ? 1 : 0;
      srcp = arr + ((size_t)(s * 16 + l15) * 1024 + n) * 64 + cc0;
    }
    af10[ks].s = *(const s16x8*)srcp;
  }

  f32x4 acc0 = {0.f, 0.f, 0.f, 0.f}, acc1 = {0.f, 0.f, 0.f, 0.f};
  // o = (oh*2+tt)*16 + l15 ; wpTb layout [d][o][ki]
  const unsigned short* wb0 = wpTb + (size_t)(oh * 32 + l15) * 320 + q * 8;
#pragma unroll 1
  for (int d = 0; d < 10; ++d) {
    const unsigned short* wd = wb0 + (size_t)d * 20480;
    f32x4 t0 = {0.f, 0.f, 0.f, 0.f}, t1 = {0.f, 0.f, 0.f, 0.f};
#pragma unroll
    for (int ks = 0; ks < 10; ++ks) {
      FragU b0, b1;
      b0.s = *(const s16x8*)(wd + ks * 32);
      b1.s = *(const s16x8*)(wd + 5120 + ks * 32);
      t0 = __builtin_amdgcn_mfma_f32_16x16x32_bf16(af10[ks].b, b0.b, t0,
                                                   0, 0, 0);
      t1 = __builtin_amdgcn_mfma_f32_16x16x32_bf16(af10[ks].b, b1.b, t1,
                                                   0, 0, 0);
    }
    const float e = emb[n * 10 + d];
#pragma unroll
    for (int rr = 0; rr < 4; ++rr) {
      acc0[rr] += e * t0[rr];
      acc1[rr] += e * t1[rr];
    }
  }

#pragma unroll
  for (int tt = 0; tt < 2; ++tt) {
    const int o = oh * 32 + tt * 16 + l15;
    float bv = 0.f;
#pragma unroll
    for (int d = 0; d < 10; ++d) bv += emb[n * 10 + d] * bp[d * 64 + o];
#pragma unroll
    for (int rr = 0; rr < 4; ++rr) {
      const int bb = q * 4 + rr;
      const float a = tt ? acc1[rr] : acc0[rr];
      out[((size_t)bb * 1024 + n) * 64 + o] = a + bv;
    }
  }
}

// ---------------------------------------------------------------------------
extern "C" void kernel_launch(void* const* d_in, const int* in_sizes, int n_in,
                              void* d_out, int out_size, void* d_ws,
                              size_t ws_size, hipStream_t stream) {
  const float* x   = (const float*)d_in[0];   // [16,1024,64]
  const float* adj = (const float*)d_in[1];   // [2,16,1024,1024]
  const float* emb = (const float*)d_in[2];   // [1024,10]
  const float* wp  = (const float*)d_in[3];   // [10,5,64,64]
  const float* bp  = (const float*)d_in[4];   // [10,64]
  float* out = (float*)d_out;                 // [16,1024,64]

  char* ws = (char*)d_ws;
  unsigned short* adjb = (unsigned short*)(ws);                      // 67 MB
  unsigned short* XT0  = (unsigned short*)(ws + ((size_t)68 << 20)); // 2 MB
  unsigned short* XT1  = (unsigned short*)(ws + ((size_t)70 << 20)); // 4 MB
  unsigned short* X0b  = (unsigned short*)(ws + ((size_t)74 << 20)); // 2 MB
  unsigned short* X1b  = (unsigned short*)(ws + ((size_t)76 << 20)); // 4 MB
  unsigned short* X2b  = (unsigned short*)(ws + ((size_t)80 << 20)); // 4 MB
  unsigned short* wpTb = (unsigned short*)(ws + ((size_t)84 << 20)); // 410 KB

  cvtprep<<<dim3(8498), dim3(256), 0, stream>>>(adj, adjb, x, wp, XT0, X0b,
                                                wpTb);
  hop1_kernel<<<dim3(8, 32), dim3(512), 0, stream>>>(adjb, XT0, X1b, XT1);
  hop2_kernel<<<dim3(8, 32), dim3(512), 0, stream>>>(adjb, XT1, X2b);
  final_kernel<<<dim3(512), dim3(256), 0, stream>>>(X0b, X1b, X2b, wpTb, emb,
                                                    bp, out);
}

// Round 9
// 262.897 us; speedup vs baseline: 1.1034x; 1.1034x over previous
//
#include <hip/hip_runtime.h>
#include <stdint.h>

// ---------------------------------------------------------------------------
// PDG2Seq_GCN: B=16, N=1024, C=O=64, D=10, CHEB_K=2 (K=5 stacked terms)
// Round 15: single-variable test on R13 (best, 259.7): hop restructured to
// 128 rows/block, 512 thr, with CORRECT occupancy declaration
// __launch_bounds__(512,4) = 4 waves/SIMD = 16 waves/CU = 2 blocks/CU
// (R14's (512,2) silently halved hop TLP to 8 waves/CU — that was the 30us
// regression; same bug class as R8's (256,2)). Halves stage-barrier rounds
// and B-panel staging redundancy at ISO-occupancy vs R13.
// Everything else = R13 verbatim: separate cvt_adj, prep (+swizzled wpTb),
// LDS-staged final. Launches: cvt_adj, prep, hop1, hop2, final.
// ---------------------------------------------------------------------------

typedef __attribute__((ext_vector_type(4))) float f32x4;
typedef __attribute__((ext_vector_type(8))) short s16x8;
typedef __attribute__((ext_vector_type(8))) __bf16 bf16x8;

__device__ __forceinline__ unsigned short f2bf(float f) {
  union { float f; uint32_t u; } v; v.f = f;
  uint32_t r = v.u + 0x7FFFu + ((v.u >> 16) & 1u);   // RNE
  return (unsigned short)(r >> 16);
}
__device__ __forceinline__ uint32_t pack2(float a, float b) {
  return (uint32_t)f2bf(a) | ((uint32_t)f2bf(b) << 16);
}

union FragU { s16x8 s; bf16x8 b; uint32_t u[4]; };

__device__ __forceinline__ void async_cp16(const void* g, void* l) {
  __builtin_amdgcn_global_load_lds(
      (const __attribute__((address_space(1))) void*)g,
      (__attribute__((address_space(3))) void*)l, 16, 0, 0);
}

// ---------------------------------------------------------------------------
// K0 cvt_adj: adj f32 [33554432] -> adjb bf16. Streaming, grid-stride.
// ---------------------------------------------------------------------------
__global__ __launch_bounds__(256) void cvt_adj(const float* __restrict__ adj,
                                               unsigned short* __restrict__ adjb) {
  const size_t stride = (size_t)gridDim.x * 256 * 8;
  for (size_t p = ((size_t)blockIdx.x * 256 + threadIdx.x) * 8;
       p < 33554432u; p += stride) {
    f32x4 a = *(const f32x4*)(adj + p);
    f32x4 b = *(const f32x4*)(adj + p + 4);
    union { s16x8 s; uint32_t u[4]; } o;
    o.u[0] = pack2(a[0], a[1]);
    o.u[1] = pack2(a[2], a[3]);
    o.u[2] = pack2(b[0], b[1]);
    o.u[3] = pack2(b[2], b[3]);
    *(s16x8*)(adjb + p) = o.s;
  }
}

// ---------------------------------------------------------------------------
// K1 prep: blocks 0..255: x -> XT0 bf16 [b][c][n] + X0b bf16 [b][n][c];
//          blocks 256..305: wp -> swizzled bf16 wpTb [d][o][384-chunkspace].
// ---------------------------------------------------------------------------
__global__ __launch_bounds__(256) void prep(const float* __restrict__ x,
                                            const float* __restrict__ wp,
                                            unsigned short* __restrict__ XT0,
                                            unsigned short* __restrict__ X0b,
                                            unsigned short* __restrict__ wpTb) {
  __shared__ __align__(16) char smem[17160];
  const int tid = threadIdx.x;
  const int bid = blockIdx.x;
  if (bid < 256) {
    unsigned short (*tl)[72] = (unsigned short(*)[72])smem;
    const int b = bid >> 4, n0 = (bid & 15) * 64;
    {
      const int c4 = (tid & 15) * 4;
#pragma unroll
      for (int i = 0; i < 4; ++i) {
        const int row = (tid >> 4) + i * 16;
        f32x4 v =
            *(const f32x4*)(x + ((size_t)(b * 1024 + n0 + row)) * 64 + c4);
        const uint32_t w0 = pack2(v[0], v[1]);
        const uint32_t w1 = pack2(v[2], v[3]);
        *(uint32_t*)&tl[row][c4]     = w0;
        *(uint32_t*)&tl[row][c4 + 2] = w1;
        const uint64_t wq = (uint64_t)w0 | ((uint64_t)w1 << 32);
        *(uint64_t*)(X0b + ((size_t)(b * 1024 + n0 + row)) * 64 + c4) = wq;
      }
    }
    __syncthreads();
    {
      const int c = tid >> 2;
      const int nch = (tid & 3) * 16;
      s16x8 s0, s1;
#pragma unroll
      for (int j = 0; j < 8; ++j) {
        s0[j] = (short)tl[nch + j][c];
        s1[j] = (short)tl[nch + 8 + j][c];
      }
      unsigned short* p = XT0 + (size_t)(b * 64 + c) * 1024 + n0 + nch;
      *(s16x8*)p = s0;
      *(s16x8*)(p + 8) = s1;
    }
  } else {
    float (*tl)[65] = (float(*)[65])smem;
    const int jj = bid - 256;
    const int d = jj / 5, ki0 = (jj % 5) * 64;
    const float* src = wp + (size_t)d * 20480;
    {
      const int o4 = (tid & 15) * 4;
#pragma unroll
      for (int i = 0; i < 4; ++i) {
        const int row = (tid >> 4) + i * 16;
        f32x4 v = *(const f32x4*)(src + (size_t)(ki0 + row) * 64 + o4);
        tl[row][o4] = v[0]; tl[row][o4 + 1] = v[1];
        tl[row][o4 + 2] = v[2]; tl[row][o4 + 3] = v[3];
      }
    }
    __syncthreads();
    {
      const int o = tid >> 2;
      const int kch = (tid & 3) * 16;
      s16x8 s0, s1;
#pragma unroll
      for (int j = 0; j < 8; ++j) {
        s0[j] = (short)f2bf(tl[kch + j][o]);
        s1[j] = (short)f2bf(tl[kch + 8 + j][o]);
      }
      const int c0 = (ki0 + kch) >> 3;                 // 16B chunk index
      unsigned short* base = wpTb + (size_t)d * 24576 + (size_t)o * 384;
      *(s16x8*)(base + ((c0) ^ (o & 7)) * 8) = s0;
      *(s16x8*)(base + ((c0 + 1) ^ (o & 7)) * 8) = s1;
    }
  }
}

// ---------------------------------------------------------------------------
// hop body: out[128 rows][64] = A[1024x1024]bf16 @ X[1024x64]bf16.
// 512 thr / 8 waves, 16 rows/wave. Per stage: A 16KB (2 DMA/wave) + B 8KB
// (1 DMA/wave), 2-buf 48KB LDS, 1 __syncthreads per stage, XOR chunk
// swizzle on the global source, swizzled frag reads.
// ---------------------------------------------------------------------------
__device__ __forceinline__ void hop_body(
    char* smem, const unsigned short* __restrict__ A,
    const unsigned short* __restrict__ XT, unsigned short* __restrict__ Xoutb,
    unsigned short* __restrict__ XTout, int write_xt, int rowbase) {
  const int tid = threadIdx.x;
  const int wave = tid >> 6, lane = tid & 63;
  const int l15 = lane & 15, q = lane >> 4;

  unsigned short* const Ast = (unsigned short*)smem;           // [2][128][64]
  unsigned short* const Bst = (unsigned short*)smem + 16384;   // [2][64][64]

  const int sub = lane >> 3;            // row-in-8
  const int ch = lane & 7;              // 8-short chunk
  const unsigned short* asrc[2];
  int aldso[2];
#pragma unroll
  for (int i = 0; i < 2; ++i) {
    const int r = wave * 16 + i * 8 + sub;
    asrc[i] = A + (size_t)(rowbase + r) * 1024 + (ch ^ sub) * 8;
    aldso[i] = (wave * 16 + i * 8) * 64;
  }
  const int rc = wave * 8 + (lane >> 3);        // B row = channel c
  const unsigned short* bsrc =
      XT + (size_t)rc * 1024 + ((lane & 7) ^ (rc & 7)) * 8;
  const int bldso = wave * 512;

  f32x4 acc[4];
#pragma unroll
  for (int t = 0; t < 4; ++t) acc[t] = (f32x4){0.f, 0.f, 0.f, 0.f};

  auto issue = [&](int s, int k0) {
#pragma unroll
    for (int i = 0; i < 2; ++i)
      async_cp16(asrc[i] + k0, Ast + s * 8192 + aldso[i]);
    async_cp16(bsrc + k0, Bst + s * 4096 + bldso);
  };
  const int sw = l15 & 7;
  auto compute = [&](int s) {
    const unsigned short* Ab = Ast + s * 8192 + (wave * 16 + l15) * 64;
    const unsigned short* Bb = Bst + s * 4096 + l15 * 64;
#pragma unroll
    for (int h = 0; h < 2; ++h) {
      const int cko = ((h * 4 + q) ^ sw) * 8;
      FragU af;
      af.s = *(const s16x8*)(Ab + cko);
#pragma unroll
      for (int t = 0; t < 4; ++t) {
        FragU bf;
        bf.s = *(const s16x8*)(Bb + t * 1024 + cko);
        acc[t] = __builtin_amdgcn_mfma_f32_16x16x32_bf16(af.b, bf.b, acc[t],
                                                         0, 0, 0);
      }
    }
  };

  issue(0, 0);
#pragma unroll 1
  for (int kt = 0; kt < 16; ++kt) {
    const int cur = kt & 1;
    __syncthreads();                   // stage kt landed (vmcnt drain)
    if (kt + 1 < 16) issue(cur ^ 1, (kt + 1) * 64);
    compute(cur);
  }

  // Epilogue: 128x64 transpose via LDS (reuse stage memory), bf16 write-out
  __syncthreads();
  float (*tile)[65] = (float(*)[65])smem;              // 33.3 KB
#pragma unroll
  for (int t = 0; t < 4; ++t)
#pragma unroll
    for (int rr = 0; rr < 4; ++rr)
      tile[wave * 16 + q * 4 + rr][t * 16 + l15] = acc[t][rr];
  __syncthreads();

  {  // node-major bf16 [n][c]
    const int row = tid >> 2;                  // 0..127
    const int cb = (tid & 3) * 16;
    unsigned short* __restrict__ outp =
        Xoutb + (size_t)(rowbase + row) * 64 + cb;
    s16x8 s0, s1;
#pragma unroll
    for (int j = 0; j < 8; ++j) {
      s0[j] = (short)f2bf(tile[row][cb + j]);
      s1[j] = (short)f2bf(tile[row][cb + 8 + j]);
    }
    *(s16x8*)outp = s0;
    *(s16x8*)(outp + 8) = s1;
  }
  if (write_xt) {  // c-major bf16 [c][n] for next hop
    const int c = tid >> 3;                    // 0..63
    const int nch = (tid & 7) * 16;            // 0..112
    unsigned short* __restrict__ xtp = XTout + (size_t)c * 1024 + rowbase + nch;
    s16x8 s0, s1;
#pragma unroll
    for (int j = 0; j < 8; ++j) {
      s0[j] = (short)f2bf(tile[nch + j][c]);
      s1[j] = (short)f2bf(tile[nch + 8 + j][c]);
    }
    *(s16x8*)xtp = s0;
    *(s16x8*)(xtp + 8) = s1;
  }
}

// ---------------------------------------------------------------------------
// K2 hop1: adjb bf16 (LLC-warm) -> X1b + XT1. grid (8,32), 512 thr,
// (512,4) = 16 waves/CU = 2 blocks/CU.
// ---------------------------------------------------------------------------
__global__ __launch_bounds__(512, 4) void hop1_kernel(
    const unsigned short* __restrict__ adjb,
    const unsigned short* __restrict__ XT0, unsigned short* __restrict__ X1b,
    unsigned short* __restrict__ XT1) {
  __shared__ __align__(16) char smem[49152];
  const int bx = blockIdx.x, slice = blockIdx.y, b = slice & 15;
  hop_body(smem, adjb + (size_t)slice * 1048576, XT0 + (size_t)b * 65536,
           X1b + (size_t)slice * 65536, XT1 + (size_t)slice * 65536, 1,
           bx * 128);
}

// ---------------------------------------------------------------------------
// K3 hop2, reversed block order (LLC-hot adjb tail first).
// ---------------------------------------------------------------------------
__global__ __launch_bounds__(512, 4) void hop2_kernel(
    const unsigned short* __restrict__ adjb,
    const unsigned short* __restrict__ XT1, unsigned short* __restrict__ X2b) {
  __shared__ __align__(16) char smem[49152];
  const int bx = 7 - (int)blockIdx.x;
  const int slice = 31 - (int)blockIdx.y;
  hop_body(smem, adjb + (size_t)slice * 1048576, XT1 + (size_t)slice * 65536,
           X2b + (size_t)slice * 65536, (unsigned short*)0, 0, bx * 128);
}

// ---------------------------------------------------------------------------
// K4 final (R13, proven): out[b,n,o] = sum_d emb[n,d]*(xg@WpT_d) + bias.
// Per d: stage swizzled wpTb[d] (48 KB) into LDS via DMA, 20 MFMA/wave.
// 4 nodes/block (nd = wave>>1), 2 o-halves (oh). grid 256, block 512.
// ---------------------------------------------------------------------------
__global__ __launch_bounds__(512, 4) void final_kernel(
    const unsigned short* __restrict__ X0b,
    const unsigned short* __restrict__ X1b,
    const unsigned short* __restrict__ X2b,
    const unsigned short* __restrict__ wpTb, const float* __restrict__ emb,
    const float* __restrict__ bp, float* __restrict__ out) {
  __shared__ __align__(16) unsigned short wd[64][384];          // 48 KB
  const int tid = threadIdx.x, bid = blockIdx.x;
  const int wave = tid >> 6, lane = tid & 63;
  const int l15 = lane & 15, q = lane >> 4;
  const int nd = wave >> 1, oh = wave & 1;
  const int n = bid * 4 + nd;
  const int sw2 = l15 & 7;

  FragU af10[10];
#pragma unroll
  for (int ks = 0; ks < 10; ++ks) {
    const int k = ks >> 1;
    const int cc0 = (ks & 1) * 32 + q * 8;
    const unsigned short* srcp;
    if (k == 0) {
      srcp = X0b + ((size_t)l15 * 1024 + n) * 64 + cc0;
    } else {
      const unsigned short* arr = (k == 1 || k == 3) ? X1b : X2b;
      const int s = (k >= 3) ? 1 : 0;
      srcp = arr + ((size_t)(s * 16 + l15) * 1024 + n) * 64 + cc0;
    }
    af10[ks].s = *(const s16x8*)srcp;
  }

  f32x4 acc0 = {0.f, 0.f, 0.f, 0.f}, acc1 = {0.f, 0.f, 0.f, 0.f};
  // Per-lane global source; LDS dest wave-uniform + lane*16B (linear copy,
  // swizzle baked into wpTb's global layout).
  const unsigned short* wsrc = wpTb + (size_t)wave * 3072 + lane * 8;
  unsigned short* wdst = (unsigned short*)wd + wave * 3072;
#pragma unroll 1
  for (int d = 0; d < 10; ++d) {
    if (d) __syncthreads();                          // WAR vs prev compute
#pragma unroll
    for (int i = 0; i < 6; ++i)
      async_cp16(wsrc + (size_t)d * 24576 + i * 512, wdst + i * 512);
    asm volatile("s_waitcnt vmcnt(0)" ::: "memory");
    __builtin_amdgcn_sched_barrier(0);
    __syncthreads();
    f32x4 t0 = {0.f, 0.f, 0.f, 0.f}, t1 = {0.f, 0.f, 0.f, 0.f};
#pragma unroll
    for (int ks = 0; ks < 10; ++ks) {
      const int p = ((ks * 4 + q) ^ sw2) * 8;
      FragU b0, b1;
      b0.s = *(const s16x8*)&wd[oh * 32 + l15][p];
      b1.s = *(const s16x8*)&wd[oh * 32 + 16 + l15][p];
      t0 = __builtin_amdgcn_mfma_f32_16x16x32_bf16(af10[ks].b, b0.b, t0,
                                                   0, 0, 0);
      t1 = __builtin_amdgcn_mfma_f32_16x16x32_bf16(af10[ks].b, b1.b, t1,
                                                   0, 0, 0);
    }
    const float e = emb[n * 10 + d];
#pragma unroll
    for (int rr = 0; rr < 4; ++rr) {
      acc0[rr] += e * t0[rr];
      acc1[rr] += e * t1[rr];
    }
  }

#pragma unroll
  for (int tt = 0; tt < 2; ++tt) {
    const int o = oh * 32 + tt * 16 + l15;
    float bv = 0.f;
#pragma unroll
    for (int d = 0; d < 10; ++d) bv += emb[n * 10 + d] * bp[d * 64 + o];
#pragma unroll
    for (int rr = 0; rr < 4; ++rr) {
      const int bb = q * 4 + rr;
      const float a = tt ? acc1[rr] : acc0[rr];
      out[((size_t)bb * 1024 + n) * 64 + o] = a + bv;
    }
  }
}

// ---------------------------------------------------------------------------
extern "C" void kernel_launch(void* const* d_in, const int* in_sizes, int n_in,
                              void* d_out, int out_size, void* d_ws,
                              size_t ws_size, hipStream_t stream) {
  const float* x   = (const float*)d_in[0];   // [16,1024,64]
  const float* adj = (const float*)d_in[1];   // [2,16,1024,1024]
  const float* emb = (const float*)d_in[2];   // [1024,10]
  const float* wp  = (const float*)d_in[3];   // [10,5,64,64]
  const float* bp  = (const float*)d_in[4];   // [10,64]
  float* out = (float*)d_out;                 // [16,1024,64]

  char* ws = (char*)d_ws;
  unsigned short* adjb = (unsigned short*)(ws);                      // 67 MB
  unsigned short* XT0  = (unsigned short*)(ws + ((size_t)68 << 20)); // 2 MB
  unsigned short* XT1  = (unsigned short*)(ws + ((size_t)70 << 20)); // 4 MB
  unsigned short* X0b  = (unsigned short*)(ws + ((size_t)74 << 20)); // 2 MB
  unsigned short* X1b  = (unsigned short*)(ws + ((size_t)76 << 20)); // 4 MB
  unsigned short* X2b  = (unsigned short*)(ws + ((size_t)80 << 20)); // 4 MB
  unsigned short* wpTb = (unsigned short*)(ws + ((size_t)84 << 20)); // 480 KB

  cvt_adj<<<dim3(8192), dim3(256), 0, stream>>>(adj, adjb);
  prep<<<dim3(306), dim3(256), 0, stream>>>(x, wp, XT0, X0b, wpTb);
  hop1_kernel<<<dim3(8, 32), dim3(512), 0, stream>>>(adjb, XT0, X1b, XT1);
  hop2_kernel<<<dim3(8, 32), dim3(512), 0, stream>>>(adjb, XT1, X2b);
  final_kernel<<<dim3(256), dim3(512), 0, stream>>>(X0b, X1b, X2b, wpTb, emb,
                                                    bp, out);
}